// Round 19
// baseline (255.671 us; speedup 1.0000x reference)
//
#include <hip/hip_runtime.h>
#include <hip/hip_bf16.h>

// out[n] = sum_m exp(-GAMMA * max(||x_n||^2 + ||y_m||^2 - 2 x.y, 0)) * W[m] + b
// n=16384, m=8192, d=512.
// Round 19: r2's 256x256 8-phase template (correct cache: FETCH 70MB,
// conflicts 0) with r4's PROVEN SYNC MECHANICS swapped in -- the one
// combination never tested. Only diff vs r2: BAR = builtin s_barrier (no
// "memory" clobber), VM4/VM0 = naked counted s_waitcnt. This is the m201
// template proper: counted vmcnt keeps 4 loads in flight across barriers
// (T3+T4); r2's clobbered barriers forced drain-0 (-38-73% per m218).
//
// Workspace: Xb bf16[16384*512] @0, Yb bf16[8192*512] @16777216,
//            x2 f32[16384] @25165824, y2 f32[8192] @25231360.

#define GAMMA 0.002f

typedef __bf16 bf16x8 __attribute__((ext_vector_type(8)));
typedef float  f32x4  __attribute__((ext_vector_type(4)));
typedef __attribute__((address_space(3))) void lds_void_t;
typedef __attribute__((address_space(1))) const void gl_void_t;

// ---------------- prep: f32 -> bf16 + row squared-norm (one wave per row, d=512)
__global__ __launch_bounds__(256) void prep_kernel(const float* __restrict__ src,
                                                   __bf16* __restrict__ dst,
                                                   float* __restrict__ norms,
                                                   int nrows) {
    const int wid  = threadIdx.x >> 6;
    const int lane = threadIdx.x & 63;
    const int row  = blockIdx.x * 4 + wid;
    if (row >= nrows) return;
    const float4* s = reinterpret_cast<const float4*>(src + (size_t)row * 512);
    float4 v0 = s[lane * 2];
    float4 v1 = s[lane * 2 + 1];
    float acc = v0.x * v0.x + v0.y * v0.y + v0.z * v0.z + v0.w * v0.w
              + v1.x * v1.x + v1.y * v1.y + v1.z * v1.z + v1.w * v1.w;
    bf16x8 o;
    o[0] = (__bf16)v0.x; o[1] = (__bf16)v0.y; o[2] = (__bf16)v0.z; o[3] = (__bf16)v0.w;
    o[4] = (__bf16)v1.x; o[5] = (__bf16)v1.y; o[6] = (__bf16)v1.z; o[7] = (__bf16)v1.w;
    *reinterpret_cast<bf16x8*>(dst + (size_t)row * 512 + lane * 8) = o;
#pragma unroll
    for (int off = 32; off >= 1; off >>= 1) acc += __shfl_xor(acc, off, 64);
    if (lane == 0) norms[row] = acc;
}

__global__ void init_out(float* __restrict__ out, const float* __restrict__ b, int n) {
    int i = blockIdx.x * blockDim.x + threadIdx.x;
    if (i < n) out[i] = b[0];
}

// ---------------- LDS geometry (r2-verified) ----------------
// A: [dbuf d][half h][row r 0..127][k 0..63] bf16 at byte (d*2+h)*16384 + r*128 + col
// B: same at +65536.  Granule swizzle: 16B granule g (=k/8) stored at column
// g' = g ^ (r&7).  Staged linearly via global_load_lds with the inverse
// permutation applied to the per-lane GLOBAL source address.

#define DSR_A(d, rb, ks) (*reinterpret_cast<const bf16x8*>( \
    &smem[(aBase + (d)*32768 + (rb)*2048) ^ ((ks)*64)]))
#define DSR_B(d, cb, ks) (*reinterpret_cast<const bf16x8*>( \
    &smem[(bBase + (d)*32768 + (cb)*2048) ^ ((ks)*64)]))

// Stage one half-tile (128 rows x 64 k): this wave's 16 rows via 2 x 1KB loads.
#define STAGE(GW, MOFF, D, H, KT) do { \
    __builtin_amdgcn_global_load_lds((gl_void_t*)((GW) + (size_t)((H)*128)*512 + (KT)*64), \
        (lds_void_t*)(smem + (MOFF) + ((D)*2+(H))*16384 + swave), 16, 0, 0); \
    __builtin_amdgcn_global_load_lds((gl_void_t*)((GW) + (size_t)((H)*128 + 8)*512 + (KT)*64), \
        (lds_void_t*)(smem + (MOFF) + ((D)*2+(H))*16384 + swave + 1024), 16, 0, 0); \
} while (0)

// PROVEN sync mechanics (m201/m218 template; the ONLY change vs r2):
#define BAR __builtin_amdgcn_s_barrier()
#define VM4 asm volatile("s_waitcnt vmcnt(4)")
#define VM0 asm volatile("s_waitcnt vmcnt(0)")
#define VMNONE ((void)0)

// One phase: ds-reads || stage 1 half-tile -> [vmcnt] -> barrier -> 16 MFMA -> barrier
#define PHASE(d, q, READB, STAGE_STMT, VMSTMT) do { \
    bf16x8 a00 = DSR_A(d, 2*(q),   0); \
    bf16x8 a01 = DSR_A(d, 2*(q),   1); \
    bf16x8 a10 = DSR_A(d, 2*(q)+1, 0); \
    bf16x8 a11 = DSR_A(d, 2*(q)+1, 1); \
    if (READB) { \
        _Pragma("unroll") \
        for (int cb = 0; cb < 4; ++cb) { \
            bfr[cb][0] = DSR_B(d, cb, 0); \
            bfr[cb][1] = DSR_B(d, cb, 1); \
        } \
    } \
    STAGE_STMT; \
    VMSTMT; \
    BAR; \
    __builtin_amdgcn_s_setprio(1); \
    _Pragma("unroll") \
    for (int cb = 0; cb < 4; ++cb) { \
        acc[2*(q)][cb]   = __builtin_amdgcn_mfma_f32_16x16x32_bf16(a00, bfr[cb][0], acc[2*(q)][cb],   0, 0, 0); \
        acc[2*(q)][cb]   = __builtin_amdgcn_mfma_f32_16x16x32_bf16(a01, bfr[cb][1], acc[2*(q)][cb],   0, 0, 0); \
        acc[2*(q)+1][cb] = __builtin_amdgcn_mfma_f32_16x16x32_bf16(a10, bfr[cb][0], acc[2*(q)+1][cb], 0, 0, 0); \
        acc[2*(q)+1][cb] = __builtin_amdgcn_mfma_f32_16x16x32_bf16(a11, bfr[cb][1], acc[2*(q)+1][cb], 0, 0, 0); \
    } \
    __builtin_amdgcn_s_setprio(0); \
    BAR; \
} while (0)

// grid: 64 tile_n x 32 tile_m = 2048 blocks, 512 threads (8 waves, 2x4).
__global__ __launch_bounds__(512, 2) void rbf_gemm(
    const __bf16* __restrict__ Xb, const __bf16* __restrict__ Yb,
    const float* __restrict__ x2, const float* __restrict__ y2,
    const float* __restrict__ W, float* __restrict__ out) {
    __shared__ __align__(128) char smem[131072];

    const int tid  = threadIdx.x;
    const int wid  = tid >> 6;
    const int lane = tid & 63;
    const int wr   = wid >> 2;      // 0..1 (row half)
    const int wc   = wid & 3;       // 0..3 (col quarter)

    // XCD-bijective swizzle (r2-verified: FETCH 70MB): xcd gets 8 consecutive
    // tile_n rows, sweeps tile_m.
    const int xcd    = blockIdx.x & 7;
    const int idx    = blockIdx.x >> 3;          // 0..255
    const int tile_m = idx >> 3;                 // 0..31
    const int tile_n = xcd * 8 + (idx & 7);      // 0..63
    const int tnBase = tile_n * 256;
    const int tmBase = tile_m * 256;

    // ds_read per-lane bases (byte offsets into smem)
    const int rl   = lane & 15;
    const int cb0  = (((lane >> 4) ^ (lane & 7)) & 7) * 16;       // swizzled col, ks=0
    const int aBase = wr * 16384 + rl * 128 + cb0;
    const int bBase = 65536 + (wc >> 1) * 16384 + ((wc & 1) * 64 + rl) * 128 + cb0;

    // staging: per-lane pre-swizzled global offset (elems) + wave LDS window
    const int gOff  = (lane >> 3) * 512 + (((lane & 7) ^ (lane >> 3)) * 8);
    const int swave = wid * 2048;
    const __bf16* sA = Xb + (size_t)(tnBase + wid * 16) * 512 + gOff;
    const __bf16* sB = Yb + (size_t)(tmBase + wid * 16) * 512 + gOff;

    f32x4  acc[8][4] = {};
    bf16x8 bfr[4][2];

    // ---- prologue: tile0 A+B into dbuf0, tile1 B into dbuf1
    STAGE(sA, 0,     0, 0, 0);
    STAGE(sA, 0,     0, 1, 0);
    STAGE(sB, 65536, 0, 0, 0);
    STAGE(sB, 65536, 0, 1, 0);
    STAGE(sB, 65536, 1, 0, 1);
    STAGE(sB, 65536, 1, 1, 1);
    VM4;                      // tile0 A+B resident; tile1 B (4 loads) in flight
    BAR;

    // ---- steady state: iter i computes K-tiles 2i (dbuf0), 2i+1 (dbuf1)
    for (int i = 0; i < 3; ++i) {
        const int kt1 = 2 * i + 1, kt2 = 2 * i + 2, kt3 = 2 * i + 3;
        PHASE(0, 0, true,  STAGE(sA, 0,     1, 0, kt1), VMNONE);
        PHASE(0, 1, false, STAGE(sA, 0,     1, 1, kt1), VMNONE);
        PHASE(0, 2, false, STAGE(sB, 65536, 0, 0, kt2), VMNONE);
        PHASE(0, 3, false, STAGE(sB, 65536, 0, 1, kt2), VM4);
        PHASE(1, 0, true,  STAGE(sA, 0,     0, 0, kt2), VMNONE);
        PHASE(1, 1, false, STAGE(sA, 0,     0, 1, kt2), VMNONE);
        PHASE(1, 2, false, STAGE(sB, 65536, 1, 0, kt3), VMNONE);
        PHASE(1, 3, false, STAGE(sB, 65536, 1, 1, kt3), VM4);
    }
    // ---- tail: K-tiles 6 (dbuf0), 7 (dbuf1); only A1[t7] still to stage
    PHASE(0, 0, true,  STAGE(sA, 0, 1, 0, 7), VMNONE);
    PHASE(0, 1, false, STAGE(sA, 0, 1, 1, 7), VMNONE);
    PHASE(0, 2, false, VMNONE,                VMNONE);
    PHASE(0, 3, false, VMNONE,                VM0);
    PHASE(1, 0, true,  VMNONE,                VMNONE);
    PHASE(1, 1, false, VMNONE,                VMNONE);
    PHASE(1, 2, false, VMNONE,                VMNONE);
    PHASE(1, 3, false, VMNONE,                VMNONE);

    // ---- epilogue: exp + weighted row-sum, 16-lane reduce, atomic into out
    // C/D layout (16x16x32): col = lane&15 (m), row = (lane>>4)*4 + reg (n)
    const int lcol = lane & 15, lrow = lane >> 4;
    float y2v[4], wv[4];
#pragma unroll
    for (int cb = 0; cb < 4; ++cb) {
        int m = tmBase + wc * 64 + cb * 16 + lcol;
        y2v[cb] = y2[m];
        wv[cb]  = W[m];
    }
#pragma unroll
    for (int rb = 0; rb < 8; ++rb) {
#pragma unroll
        for (int i2 = 0; i2 < 4; ++i2) {
            const int n = tnBase + wr * 128 + rb * 16 + lrow * 4 + i2;
            const float x2n = x2[n];
            float s = 0.f;
#pragma unroll
            for (int cb = 0; cb < 4; ++cb) {
                float d2 = x2n + y2v[cb] - 2.0f * acc[rb][cb][i2];
                d2 = fmaxf(d2, 0.f);
                s += __expf(-GAMMA * d2) * wv[cb];
            }
#pragma unroll
            for (int off = 1; off < 16; off <<= 1) s += __shfl_xor(s, off, 64);
            if (lcol == 0) atomicAdd(&out[n], s);
        }
    }
}

extern "C" void kernel_launch(void* const* d_in, const int* in_sizes, int n_in,
                              void* d_out, int out_size, void* d_ws, size_t ws_size,
                              hipStream_t stream) {
    const float* X = (const float*)d_in[0];   // 16384 x 512
    const float* Y = (const float*)d_in[1];   //  8192 x 512
    const float* W = (const float*)d_in[2];   // 8192
    const float* b = (const float*)d_in[3];   // 1
    float* out = (float*)d_out;               // 16384

    char* ws = (char*)d_ws;
    __bf16* Xb = (__bf16*)(ws);
    __bf16* Yb = (__bf16*)(ws + 16777216);
    float*  x2 = (float*)(ws + 16777216 + 8388608);
    float*  y2 = (float*)(ws + 16777216 + 8388608 + 65536);

    prep_kernel<<<4096, 256, 0, stream>>>(X, Xb, x2, 16384);
    prep_kernel<<<2048, 256, 0, stream>>>(Y, Yb, y2, 8192);
    init_out<<<64, 256, 0, stream>>>(out, b, 16384);
    rbf_gemm<<<2048, 512, 0, stream>>>(Xb, Yb, x2, y2, W, out);
}

// Round 20
// 142.609 us; speedup vs baseline: 1.7928x; 1.7928x over previous
//
#include <hip/hip_runtime.h>
#include <hip/hip_bf16.h>

// out[n] = b + e_x[n] * sum_m exp(2*GAMMA*dot(x_n,y_m)) * c[m]
// n=16384, m=8192, d=512.
// Round 20 (final): r18's gemm verbatim (best: 64x64 wave tile, B-from-L2-
// frag-regs, read-only LDS, no main-loop barriers, 2 blocks/CU, rowsum regs,
// end-only reduce+atomic; gemm ~130us = 1058 TF, MfmaUtil 50, no spill).
// Only change: prep_x + prep_y FUSED into one launch (rows 0..16383 = X path
// w/ out=b init; 16384..24575 = Y path) -> overlapped prep streams, one
// fewer dispatch. 2 launches total.
//
// Workspace: Xb bf16[16384*512] @0, Ybt bf16[8192*512] @16777216 (frag layout),
//            ex f32[16384] @25165824, cw f32[8192] @25231360.

#define GAMMA 0.002f

typedef __bf16 bf16x8 __attribute__((ext_vector_type(8)));
typedef float  f32x4  __attribute__((ext_vector_type(4)));
typedef __attribute__((address_space(3))) void lds_void_t;
typedef __attribute__((address_space(1))) const void gl_void_t;

// ---------------- fused prep: one wave per row.
// rows 0..16383: X -> Xb row-major bf16, ex = exp(-g*||x||^2), out = b.
// rows 16384..24575: m = row-16384: Y -> Ybt 16x16x32-fragment layout
//   (elem idx: ((lane>>2)*512 + (m>>4))*512 + ((lane&3)*16 + (m&15))*8),
//   cw = exp(-g*||y||^2) * W[m].
__global__ __launch_bounds__(256) void prep_fused(
    const float* __restrict__ X, const float* __restrict__ Y,
    const float* __restrict__ W, const float* __restrict__ bias,
    __bf16* __restrict__ Xb, __bf16* __restrict__ Ybt,
    float* __restrict__ ex, float* __restrict__ cw,
    float* __restrict__ out) {
    const int wid  = threadIdx.x >> 6;
    const int lane = threadIdx.x & 63;
    const int row  = blockIdx.x * 4 + wid;
    const bool isX = row < 16384;
    const int  m   = row - 16384;

    const float* srcRow = isX ? (X + (size_t)row * 512) : (Y + (size_t)m * 512);
    const float4* s = reinterpret_cast<const float4*>(srcRow);
    float4 v0 = s[lane * 2];
    float4 v1 = s[lane * 2 + 1];
    float acc = v0.x * v0.x + v0.y * v0.y + v0.z * v0.z + v0.w * v0.w
              + v1.x * v1.x + v1.y * v1.y + v1.z * v1.z + v1.w * v1.w;
    bf16x8 o;
    o[0] = (__bf16)v0.x; o[1] = (__bf16)v0.y; o[2] = (__bf16)v0.z; o[3] = (__bf16)v0.w;
    o[4] = (__bf16)v1.x; o[5] = (__bf16)v1.y; o[6] = (__bf16)v1.z; o[7] = (__bf16)v1.w;

    if (isX) {
        *reinterpret_cast<bf16x8*>(Xb + (size_t)row * 512 + lane * 8) = o;
    } else {
        const size_t idx = ((size_t)(lane >> 2) * 512 + (m >> 4)) * 512
                         + ((lane & 3) * 16 + (m & 15)) * 8;
        *reinterpret_cast<bf16x8*>(Ybt + idx) = o;
    }
#pragma unroll
    for (int off = 32; off >= 1; off >>= 1) acc += __shfl_xor(acc, off, 64);
    if (lane == 0) {
        const float e = __expf(-GAMMA * acc);
        if (isX) {
            ex[row]  = e;
            out[row] = bias[0];
        } else {
            cw[m] = e * W[m];
        }
    }
}

// ---------------- LDS (80KB/block): A @0: [q 16][rb 4][1KB] k-major frag
// blocks (lane*16 read, conflict-free); cw @65536: 16KB (block's col-half).

// chunk C 0..127: q = C&15, panel p = C>>4 (8 panels x 512 cols).
// Wave owns colblocks cbgBase + p*32 .. +3 (64 cols of the panel).
#define LOADB(B, C) do { \
    const int q_ = (C) & 15, p_ = (C) >> 4; \
    const __bf16* bp_ = Ybt + ((size_t)q_ * 512 + cbgBase + p_ * 32) * 512 + lane8; \
    B[0] = *reinterpret_cast<const bf16x8*>(bp_); \
    B[1] = *reinterpret_cast<const bf16x8*>(bp_ + 512); \
    B[2] = *reinterpret_cast<const bf16x8*>(bp_ + 1024); \
    B[3] = *reinterpret_cast<const bf16x8*>(bp_ + 1536); \
} while (0)

#define READA(A, Q) do { \
    _Pragma("unroll") \
    for (int rb = 0; rb < 4; ++rb) \
        A[rb] = *reinterpret_cast<const bf16x8*>( \
            &smem[(Q) * 4096 + rb * 1024 + lane16]); \
} while (0)

#define MFMA16(A, B) do { \
    __builtin_amdgcn_s_setprio(1); \
    _Pragma("unroll") \
    for (int rb = 0; rb < 4; ++rb) \
        _Pragma("unroll") \
        for (int cb = 0; cb < 4; ++cb) \
            acc[rb][cb] = __builtin_amdgcn_mfma_f32_16x16x32_bf16( \
                A[rb], B[cb], acc[rb][cb], 0, 0, 0); \
    __builtin_amdgcn_s_setprio(0); \
} while (0)

// grid: 512 blocks (2/CU), 512 threads (8 waves; wave tile 64 rows x 64 cols)
__global__ __launch_bounds__(512, 4) void rbf_gemm(
    const __bf16* __restrict__ Xb, const __bf16* __restrict__ Ybt,
    const float* __restrict__ ex, const float* __restrict__ cwp,
    float* __restrict__ out) {
    __shared__ __align__(128) char smem[81920];

    const int tid  = threadIdx.x;
    const int wid  = tid >> 6;
    const int lane = tid & 63;

    // XCD map (r9-proven): even XCDs -> col-half 0, odd -> 1; 64 blocks/XCD
    // share one 4MB Ybt half (L2-fit). rg = 64-row group.
    const int pid = blockIdx.x;
    const int xcd = pid & 7;
    const int j   = pid >> 3;                    // 0..63
    const int ch  = xcd & 1;
    const int rg  = (xcd >> 1) * 64 + j;         // 0..255
    const int rowBase = rg * 64;
    const int colBase = ch * 4096;
    const int cbgBase = ch * 256 + wid * 4;      // wave's colblock base per panel

    const int l15 = lane & 15, l4 = lane >> 4;
    const int lane16 = lane * 16;
    const int lane8  = lane * 8;

    // ---- prologue: A panel (64 x 1KB frag blocks, gather src) + cw -> LDS
#pragma unroll
    for (int i = 0; i < 8; ++i) {
        const int blk = wid * 8 + i;
        const int q = blk >> 2, rb = blk & 3;
        const __bf16* src = Xb + (size_t)(rowBase + rb * 16 + l15) * 512 + q * 32 + l4 * 8;
        __builtin_amdgcn_global_load_lds((gl_void_t*)src,
            (lds_void_t*)(smem + q * 4096 + rb * 1024), 16, 0, 0);
    }
#pragma unroll
    for (int i = 0; i < 2; ++i)
        __builtin_amdgcn_global_load_lds(
            (gl_void_t*)(cwp + colBase + wid * 512 + i * 256 + lane * 4),
            (lds_void_t*)(smem + 65536 + wid * 2048 + i * 1024), 16, 0, 0);
    asm volatile("s_waitcnt vmcnt(0)");
    __builtin_amdgcn_s_barrier();        // the only barrier; LDS read-only after

    f32x4 acc[4][4] = {};
    float rowsum[4][4] = {};

    bf16x8 A[4], B[4];

    // ---- main: 128 chunks (8 panels x 16 kchunks), single-buffered frags,
    // no barriers (compiler schedules; pinning measured null 3x).
    for (int c = 0; c < 128; ++c) {
        LOADB(B, c);
        READA(A, c & 15);
        MFMA16(A, B);
        if ((c & 15) == 15) {
            // ---- per-panel epilogue: acc holds full K=512; pure VALU + LDS cw
            const int p = c >> 4;
            float cv[4];
#pragma unroll
            for (int cb = 0; cb < 4; ++cb)
                cv[cb] = *reinterpret_cast<const float*>(
                    &smem[65536 + (p * 512 + wid * 64 + cb * 16 + l15) * 4]);
#pragma unroll
            for (int rb = 0; rb < 4; ++rb)
#pragma unroll
                for (int i2 = 0; i2 < 4; ++i2) {
                    float s = rowsum[rb][i2];
#pragma unroll
                    for (int cb = 0; cb < 4; ++cb)
                        s += __expf(0.004f * acc[rb][cb][i2]) * cv[cb];
                    rowsum[rb][i2] = s;
                }
#pragma unroll
            for (int rb = 0; rb < 4; ++rb)
#pragma unroll
                for (int cb = 0; cb < 4; ++cb)
                    acc[rb][cb] = (f32x4){0.f, 0.f, 0.f, 0.f};
        }
    }

    // ---- final: 16-lane reduce + one atomic per (wave, n); out pre-init'd to b
#pragma unroll
    for (int rb = 0; rb < 4; ++rb)
#pragma unroll
        for (int i2 = 0; i2 < 4; ++i2) {
            float s = rowsum[rb][i2];
#pragma unroll
            for (int off = 1; off < 16; off <<= 1) s += __shfl_xor(s, off, 64);
            if (l15 == 0) {
                const int n = rowBase + rb * 16 + l4 * 4 + i2;
                atomicAdd(&out[n], ex[n] * s);
            }
        }
}

extern "C" void kernel_launch(void* const* d_in, const int* in_sizes, int n_in,
                              void* d_out, int out_size, void* d_ws, size_t ws_size,
                              hipStream_t stream) {
    const float* X = (const float*)d_in[0];   // 16384 x 512
    const float* Y = (const float*)d_in[1];   //  8192 x 512
    const float* W = (const float*)d_in[2];   // 8192
    const float* b = (const float*)d_in[3];   // 1
    float* out = (float*)d_out;               // 16384

    char* ws = (char*)d_ws;
    __bf16* Xb  = (__bf16*)(ws);
    __bf16* Ybt = (__bf16*)(ws + 16777216);
    float*  ex  = (float*)(ws + 16777216 + 8388608);
    float*  cw  = (float*)(ws + 16777216 + 8388608 + 65536);

    prep_fused<<<6144, 256, 0, stream>>>(X, Y, W, b, Xb, Ybt, ex, cw, out);
    rbf_gemm<<<512, 512, 0, stream>>>(Xb, Ybt, ex, cw, out);
}